// Round 9
// baseline (362.016 us; speedup 1.0000x reference)
//
#include <hip/hip_runtime.h>
#include <math.h>

#define NB 32768
#define NACC 11
#define MAXBLOCKS 2048
#define NTHREADS 256
#define WAVES_PER_BLOCK (NTHREADS / 64)

// acc indices:
// 0 beta_sq, 1 theta_sq, 2 twist_sq, 3 xyz_s, 4 xyz_ws,
// 5 uvd_masked, 6 uvd_used, 7 uvd_wsum, 8 uvd_full, 9 trans_sq, 10 scale_sq

__device__ __forceinline__ float wave_sum(float v) {
#pragma unroll
    for (int off = 1; off < 64; off <<= 1)
        v += __shfl_xor(v, off, 64);
    return v;
}

__device__ __forceinline__ float4 ld4(const float* p) {
    return *reinterpret_cast<const float4*>(p);
}

__global__ __launch_bounds__(NTHREADS) void fused_loss_kernel(
    const float* __restrict__ pred_shape,          // B x 10
    const float* __restrict__ pred_theta_mats,     // B x 216
    const float* __restrict__ pred_phi,            // B x 46
    const float* __restrict__ pred_xyz_jts_29,     // B x 87
    const float* __restrict__ nf_loss,             // B x 288
    const float* __restrict__ sigma,               // B x 288
    const float* __restrict__ pred_uvd_jts,        // B x 87
    const float* __restrict__ pred_uvd_mks,        // B x 201
    const float* __restrict__ cam_trans,           // B x 2
    const float* __restrict__ cam_scale,           // B x 1
    const float* __restrict__ target_smpl_weight,  // B x 1
    const float* __restrict__ target_beta,         // B x 10
    const float* __restrict__ target_theta,        // B x 216
    const float* __restrict__ target_theta_weight, // B x 216
    const float* __restrict__ target_twist,        // B x 46
    const float* __restrict__ target_twist_weight, // B x 46
    const float* __restrict__ target_xyz_24,       // B x 72
    const float* __restrict__ target_xyz_weight_24,// B x 72
    const float* __restrict__ target_uvd_29,       // B x 87
    const float* __restrict__ target_uvd_67,       // B x 201
    const float* __restrict__ target_weight_29,    // B x 87
    const float* __restrict__ target_weight_67,    // B x 201
    const float* __restrict__ camera_trans,        // B x 2
    const float* __restrict__ camera_scale,        // B x 1
    float* __restrict__ partials)                  // gridDim.x x NACC
{
    const int lane = threadIdx.x & 63;
    const int widx = threadIdx.x >> 6;
    const int wave_id = blockIdx.x * WAVES_PER_BLOCK + widx;
    const int nwaves = gridDim.x * WAVES_PER_BLOCK;

    const float INV_AMP = 2.5066282746310002f;   // sqrt(2*pi) = 1/AMP
    const float SQRT2   = 1.4142135623730951f;

    float acc[NACC];
#pragma unroll
    for (int i = 0; i < NACC; ++i) acc[i] = 0.f;

    for (int b = wave_id; b < NB; b += nwaves) {
        const float sw = target_smpl_weight[b];

        // ---- beta: 10 elems, mse(p*sw, t*sw) ----
        if (lane < 10) {
            float p = pred_shape[b * 10 + lane];
            float t = target_beta[b * 10 + lane];
            float d = p * sw - t * sw;
            acc[0] += d * d;
        }

        // ---- theta: 216 elems = 54 float4 (rows 16B-aligned) ----
        if (lane < 54) {
            int off = b * 216 + lane * 4;
            float4 p = ld4(pred_theta_mats + off);
            float4 t = ld4(target_theta + off);
            float4 w = ld4(target_theta_weight + off);
            float d;
            d = p.x * sw * w.x - t.x * sw * w.x; acc[1] += d * d;
            d = p.y * sw * w.y - t.y * sw * w.y; acc[1] += d * d;
            d = p.z * sw * w.z - t.z * sw * w.z; acc[1] += d * d;
            d = p.w * sw * w.w - t.w * sw * w.w; acc[1] += d * d;
        }

        // ---- twist: 46 elems, no sw ----
        if (lane < 46) {
            int off = b * 46 + lane;
            float p = pred_phi[off];
            float t = target_twist[off];
            float w = target_twist_weight[off];
            float d = p * w - t * w;
            acc[2] += d * d;
        }

        // ---- xyz: 72 elems; pred from 87-wide rows (unaligned -> scalar) ----
        float rw = 0.f;  // this lane's partial of the txw row sum
        if (lane < 18) {
            int off = b * 72 + lane * 4;
            float4 t = ld4(target_xyz_24 + off);
            float4 w = ld4(target_xyz_weight_24 + off);
            const float* pp = pred_xyz_jts_29 + b * 87 + lane * 4;
            float ta[4] = {t.x, t.y, t.z, t.w};
            float wa[4] = {w.x, w.y, w.z, w.w};
#pragma unroll
            for (int k = 0; k < 4; ++k) {
                float p = pp[k];
                float d = fabsf(p * 64.f - ta[k] * 64.f) * wa[k];
                acc[3] += d;
                rw += wa[k];
            }
        }
        acc[4] += rw;
        float row_w = wave_sum(rw);
        float sw2 = (row_w > 3.f) ? 1.f : 0.f;

        // ---- trans (2) / scale (1) with sw2 ----
        if (lane < 2) {
            float p = cam_trans[b * 2 + lane];
            float t = camera_trans[b * 2 + lane];
            float d = p * sw2 - t * sw2;
            acc[9] += d * d;
        }
        if (lane == 0) {
            float p = cam_scale[b];
            float t = camera_scale[b];
            float d = p * sw2 - t * sw2;
            acc[10] += d * d;
        }

        // ---- uvd: 288 elems; nf/sigma float4-aligned; p/t/w split at 87 ----
        const float* nf_row = nf_loss + (size_t)b * 288;
        const float* sg_row = sigma   + (size_t)b * 288;
        float samp = 0.f;
#pragma unroll
        for (int it = 0; it < 2; ++it) {
            int j = it * 256 + lane * 4;
            if (j < 288) {
                float4 nf = ld4(nf_row + j);
                float4 sg = ld4(sg_row + j);
                float nfa[4] = {nf.x, nf.y, nf.z, nf.w};
                float sga[4] = {sg.x, sg.y, sg.z, sg.w};
#pragma unroll
                for (int k = 0; k < 4; ++k) {
                    int jj = j + k;
                    float p, t, w;
                    if (jj < 87) {
                        int o = b * 87 + jj;
                        p = pred_uvd_jts[o];
                        t = target_uvd_29[o];
                        w = target_weight_29[o];
                    } else {
                        int o = b * 201 + (jj - 87);
                        p = pred_uvd_mks[o];
                        t = target_uvd_67[o];
                        w = target_weight_67[o];
                    }
                    float s = sga[k];
                    float q = (logf(s * INV_AMP) +
                               fabsf(t - p) / (SQRT2 * s + 1e-9f)) * w;
                    float e = nfa[k] * w + q;
                    samp += e;
                    acc[7] += w;
                }
            }
        }
        acc[8] += samp;                       // full (unmasked) sum
        float s_uvd = wave_sum(samp);         // per-sample sum, all lanes
        if (lane == 0 && s_uvd <= 0.f) {
            acc[5] += s_uvd;                  // masked sum
            acc[6] += 1.f;                    // used count
        }
    }

    // ---- block reduction -> per-block partials ----
    __shared__ float sacc[WAVES_PER_BLOCK][NACC];
#pragma unroll
    for (int i = 0; i < NACC; ++i) {
        float v = wave_sum(acc[i]);
        if (lane == 0) sacc[widx][i] = v;
    }
    __syncthreads();
    if (threadIdx.x < NACC) {
        float v = 0.f;
#pragma unroll
        for (int w = 0; w < WAVES_PER_BLOCK; ++w) v += sacc[w][threadIdx.x];
        partials[blockIdx.x * NACC + threadIdx.x] = v;
    }
}

__global__ __launch_bounds__(256) void finalize_kernel(
    const float* __restrict__ partials, int nblocks,
    const int* __restrict__ epoch_num_p, float* __restrict__ out)
{
    const int lane = threadIdx.x & 63;
    const int widx = threadIdx.x >> 6;
    __shared__ float sums[NACC];

    for (int i = widx; i < NACC; i += 4) {
        float v = 0.f;
        for (int p = lane; p < nblocks; p += 64)
            v += partials[p * NACC + i];
        v = wave_sum(v);
        if (lane == 0) sums[i] = v;
    }
    __syncthreads();

    if (threadIdx.x == 0) {
        const int epoch = epoch_num_p[0];
        const float Bf = (float)NB;

        float loss_beta  = sums[0] / (Bf * 10.f);
        float loss_theta = sums[1] / (Bf * 216.f);
        float loss_twist = sums[2] / (Bf * 46.f);
        float loss_xyz   = (sums[4] > 0.f) ? (sums[3] / sums[4]) : sums[3];

        float ms = (epoch > 0) ? sums[5] : sums[8];
        float us = (epoch > 0) ? sums[6] : Bf;
        float loss_uvd = (sums[7] > 0.f) ? (ms / us) : sums[8];

        float trans_loss = sums[9] / (Bf * 2.f);
        float scale_loss = sums[10] / Bf;

        float loss = loss_beta * 1.0f + loss_theta * 0.01f + loss_twist * 0.01f;
        if (epoch > 2) loss += loss_xyz * 1.0f;
        loss += loss_uvd * 1.0f;
        float cam_coef = (epoch > 2) ? 0.1f : 1.0f;
        loss = loss + cam_coef * (trans_loss + scale_loss);

        out[0] = loss;
        out[1] = loss_uvd;
        out[2] = loss_beta;
        out[3] = loss_theta;
        out[4] = loss_twist;
        out[5] = trans_loss;
        out[6] = scale_loss;
    }
}

extern "C" void kernel_launch(void* const* d_in, const int* in_sizes, int n_in,
                              void* d_out, int out_size, void* d_ws, size_t ws_size,
                              hipStream_t stream) {
    (void)in_sizes; (void)n_in; (void)out_size;

    int nblocks = MAXBLOCKS;
    size_t need = (size_t)nblocks * NACC * sizeof(float);
    if (ws_size < need) nblocks = (int)(ws_size / (NACC * sizeof(float)));
    if (nblocks < 1) nblocks = 1;

    float* partials = (float*)d_ws;

    fused_loss_kernel<<<nblocks, NTHREADS, 0, stream>>>(
        (const float*)d_in[0],  (const float*)d_in[1],  (const float*)d_in[2],
        (const float*)d_in[3],  (const float*)d_in[4],  (const float*)d_in[5],
        (const float*)d_in[6],  (const float*)d_in[7],  (const float*)d_in[8],
        (const float*)d_in[9],  (const float*)d_in[10], (const float*)d_in[11],
        (const float*)d_in[12], (const float*)d_in[13], (const float*)d_in[14],
        (const float*)d_in[15], (const float*)d_in[16], (const float*)d_in[17],
        (const float*)d_in[18], (const float*)d_in[19], (const float*)d_in[20],
        (const float*)d_in[21], (const float*)d_in[22], (const float*)d_in[23],
        partials);

    finalize_kernel<<<1, 256, 0, stream>>>(
        partials, nblocks, (const int*)d_in[24], (float*)d_out);
}

// Round 12
// 344.254 us; speedup vs baseline: 1.0516x; 1.0516x over previous
//
#include <hip/hip_runtime.h>
#include <math.h>

#define NB 32768
#define NACC 11
#define MAXBLOCKS 2048
#define NTHREADS 256
#define WAVES_PER_BLOCK (NTHREADS / 64)

// acc indices:
// 0 beta_sq, 1 theta_sq, 2 twist_sq, 3 xyz_s, 4 xyz_ws,
// 5 uvd_masked, 6 uvd_used, 7 uvd_wsum, 8 uvd_full, 9 trans_sq, 10 scale_sq

__device__ __forceinline__ float wave_sum(float v) {
#pragma unroll
    for (int off = 1; off < 64; off <<= 1)
        v += __shfl_xor(v, off, 64);
    return v;
}

__device__ __forceinline__ float4 ld4(const float* p) {
    return *reinterpret_cast<const float4*>(p);
}

__global__ __launch_bounds__(NTHREADS) void fused_loss_kernel(
    const float* __restrict__ pred_shape,          // B x 10
    const float* __restrict__ pred_theta_mats,     // B x 216
    const float* __restrict__ pred_phi,            // B x 46
    const float* __restrict__ pred_xyz_jts_29,     // B x 87
    const float* __restrict__ nf_loss,             // B x 288
    const float* __restrict__ sigma,               // B x 288
    const float* __restrict__ pred_uvd_jts,        // B x 87
    const float* __restrict__ pred_uvd_mks,        // B x 201
    const float* __restrict__ cam_trans,           // B x 2
    const float* __restrict__ cam_scale,           // B x 1
    const float* __restrict__ target_smpl_weight,  // B x 1
    const float* __restrict__ target_beta,         // B x 10
    const float* __restrict__ target_theta,        // B x 216
    const float* __restrict__ target_theta_weight, // B x 216
    const float* __restrict__ target_twist,        // B x 46
    const float* __restrict__ target_twist_weight, // B x 46
    const float* __restrict__ target_xyz_24,       // B x 72
    const float* __restrict__ target_xyz_weight_24,// B x 72
    const float* __restrict__ target_uvd_29,       // B x 87
    const float* __restrict__ target_uvd_67,       // B x 201
    const float* __restrict__ target_weight_29,    // B x 87
    const float* __restrict__ target_weight_67,    // B x 201
    const float* __restrict__ camera_trans,        // B x 2
    const float* __restrict__ camera_scale,        // B x 1
    float* __restrict__ partials)                  // NACC x gridDim.x (transposed)
{
    const int lane = threadIdx.x & 63;
    const int widx = threadIdx.x >> 6;
    const int wave_id = blockIdx.x * WAVES_PER_BLOCK + widx;
    const int nwaves = gridDim.x * WAVES_PER_BLOCK;

    const float INV_AMP = 2.5066282746310002f;   // sqrt(2*pi) = 1/AMP
    const float SQRT2   = 1.4142135623730951f;

    float acc[NACC];
#pragma unroll
    for (int i = 0; i < NACC; ++i) acc[i] = 0.f;

    for (int b = wave_id; b < NB; b += nwaves) {
        const float sw = target_smpl_weight[b];

        // ---- beta: 10 elems, mse(p*sw, t*sw) ----
        if (lane < 10) {
            float p = pred_shape[b * 10 + lane];
            float t = target_beta[b * 10 + lane];
            float d = p * sw - t * sw;
            acc[0] += d * d;
        }

        // ---- theta: 216 elems = 54 float4 (rows 16B-aligned) ----
        if (lane < 54) {
            int off = b * 216 + lane * 4;
            float4 p = ld4(pred_theta_mats + off);
            float4 t = ld4(target_theta + off);
            float4 w = ld4(target_theta_weight + off);
            float d;
            d = p.x * sw * w.x - t.x * sw * w.x; acc[1] += d * d;
            d = p.y * sw * w.y - t.y * sw * w.y; acc[1] += d * d;
            d = p.z * sw * w.z - t.z * sw * w.z; acc[1] += d * d;
            d = p.w * sw * w.w - t.w * sw * w.w; acc[1] += d * d;
        }

        // ---- twist: 46 elems, no sw ----
        if (lane < 46) {
            int off = b * 46 + lane;
            float p = pred_phi[off];
            float t = target_twist[off];
            float w = target_twist_weight[off];
            float d = p * w - t * w;
            acc[2] += d * d;
        }

        // ---- xyz: 72 elems, full-wave coalesced scalar rounds ----
        {
            const int oxyz = b * 72;
            const int opx  = b * 87;
            float rw = 0.f;
#pragma unroll
            for (int it = 0; it < 2; ++it) {
                int j = it * 64 + lane;
                if (j < 72) {
                    float t = target_xyz_24[oxyz + j];
                    float w = target_xyz_weight_24[oxyz + j];
                    float p = pred_xyz_jts_29[opx + j];
                    acc[3] += fabsf(p * 64.f - t * 64.f) * w;
                    rw += w;
                }
            }
            acc[4] += rw;
            float row_w = wave_sum(rw);
            float sw2 = (row_w > 3.f) ? 1.f : 0.f;

            // ---- trans (2) / scale (1) with sw2 ----
            if (lane < 2) {
                float p = cam_trans[b * 2 + lane];
                float t = camera_trans[b * 2 + lane];
                float d = p * sw2 - t * sw2;
                acc[9] += d * d;
            }
            if (lane == 0) {
                float p = cam_scale[b];
                float t = camera_scale[b];
                float d = p * sw2 - t * sw2;
                acc[10] += d * d;
            }
        }

        // ---- uvd: 288 elems, full-wave coalesced rounds, pointer-select ----
        {
            const float* nf_row = nf_loss + (size_t)b * 288;
            const float* sg_row = sigma   + (size_t)b * 288;
            const int oj = b * 87;          // jts row offset
            const int om = b * 201 - 87;    // mks row offset, pre-shifted by -87
            float samp = 0.f;
#pragma unroll
            for (int it = 0; it < 5; ++it) {
                int j = it * 64 + lane;
                if (j < 288) {
                    float nf = nf_row[j];
                    float sg = sg_row[j];
                    bool isj = (j < 87);
                    const float* P = isj ? (pred_uvd_jts    + oj) : (pred_uvd_mks    + om);
                    const float* T = isj ? (target_uvd_29   + oj) : (target_uvd_67   + om);
                    const float* W = isj ? (target_weight_29 + oj) : (target_weight_67 + om);
                    float p = P[j];
                    float t = T[j];
                    float w = W[j];
                    float q = (logf(sg * INV_AMP) +
                               fabsf(t - p) / (SQRT2 * sg + 1e-9f)) * w;
                    samp += nf * w + q;
                    acc[7] += w;
                }
            }
            acc[8] += samp;                       // full (unmasked) sum
            float s_uvd = wave_sum(samp);         // per-sample sum, all lanes
            if (lane == 0 && s_uvd <= 0.f) {
                acc[5] += s_uvd;                  // masked sum
                acc[6] += 1.f;                    // used count
            }
        }
    }

    // ---- block reduction -> transposed per-block partials ----
    __shared__ float sacc[WAVES_PER_BLOCK][NACC];
#pragma unroll
    for (int i = 0; i < NACC; ++i) {
        float v = wave_sum(acc[i]);
        if (lane == 0) sacc[widx][i] = v;
    }
    __syncthreads();
    if (threadIdx.x < NACC) {
        float v = 0.f;
#pragma unroll
        for (int w = 0; w < WAVES_PER_BLOCK; ++w) v += sacc[w][threadIdx.x];
        partials[threadIdx.x * gridDim.x + blockIdx.x] = v;
    }
}

__global__ __launch_bounds__(NTHREADS) void finalize_kernel(
    const float* __restrict__ partials, int nblocks,
    const int* __restrict__ epoch_num_p, float* __restrict__ out)
{
    const int tid  = threadIdx.x;
    const int lane = tid & 63;
    const int widx = tid >> 6;

    float a[NACC];
#pragma unroll
    for (int i = 0; i < NACC; ++i) a[i] = 0.f;

    // coalesced, high-MLP accumulation: 256 threads stride the transposed rows
    for (int p = tid; p < nblocks; p += NTHREADS) {
#pragma unroll
        for (int i = 0; i < NACC; ++i)
            a[i] += partials[i * nblocks + p];
    }

    __shared__ float red[NACC][WAVES_PER_BLOCK];
#pragma unroll
    for (int i = 0; i < NACC; ++i) {
        float v = wave_sum(a[i]);
        if (lane == 0) red[i][widx] = v;
    }
    __syncthreads();

    if (tid == 0) {
        float sums[NACC];
#pragma unroll
        for (int i = 0; i < NACC; ++i)
            sums[i] = red[i][0] + red[i][1] + red[i][2] + red[i][3];

        const int epoch = epoch_num_p[0];
        const float Bf = (float)NB;

        float loss_beta  = sums[0] / (Bf * 10.f);
        float loss_theta = sums[1] / (Bf * 216.f);
        float loss_twist = sums[2] / (Bf * 46.f);
        float loss_xyz   = (sums[4] > 0.f) ? (sums[3] / sums[4]) : sums[3];

        float ms = (epoch > 0) ? sums[5] : sums[8];
        float us = (epoch > 0) ? sums[6] : Bf;
        float loss_uvd = (sums[7] > 0.f) ? (ms / us) : sums[8];

        float trans_loss = sums[9] / (Bf * 2.f);
        float scale_loss = sums[10] / Bf;

        float loss = loss_beta * 1.0f + loss_theta * 0.01f + loss_twist * 0.01f;
        if (epoch > 2) loss += loss_xyz * 1.0f;
        loss += loss_uvd * 1.0f;
        float cam_coef = (epoch > 2) ? 0.1f : 1.0f;
        loss = loss + cam_coef * (trans_loss + scale_loss);

        out[0] = loss;
        out[1] = loss_uvd;
        out[2] = loss_beta;
        out[3] = loss_theta;
        out[4] = loss_twist;
        out[5] = trans_loss;
        out[6] = scale_loss;
    }
}

extern "C" void kernel_launch(void* const* d_in, const int* in_sizes, int n_in,
                              void* d_out, int out_size, void* d_ws, size_t ws_size,
                              hipStream_t stream) {
    (void)in_sizes; (void)n_in; (void)out_size;

    int nblocks = MAXBLOCKS;
    size_t need = (size_t)nblocks * NACC * sizeof(float);
    if (ws_size < need) nblocks = (int)(ws_size / (NACC * sizeof(float)));
    if (nblocks < 1) nblocks = 1;

    float* partials = (float*)d_ws;

    fused_loss_kernel<<<nblocks, NTHREADS, 0, stream>>>(
        (const float*)d_in[0],  (const float*)d_in[1],  (const float*)d_in[2],
        (const float*)d_in[3],  (const float*)d_in[4],  (const float*)d_in[5],
        (const float*)d_in[6],  (const float*)d_in[7],  (const float*)d_in[8],
        (const float*)d_in[9],  (const float*)d_in[10], (const float*)d_in[11],
        (const float*)d_in[12], (const float*)d_in[13], (const float*)d_in[14],
        (const float*)d_in[15], (const float*)d_in[16], (const float*)d_in[17],
        (const float*)d_in[18], (const float*)d_in[19], (const float*)d_in[20],
        (const float*)d_in[21], (const float*)d_in[22], (const float*)d_in[23],
        partials);

    finalize_kernel<<<1, NTHREADS, 0, stream>>>(
        partials, nblocks, (const int*)d_in[24], (float*)d_out);
}